// Round 15
// baseline (399.409 us; speedup 1.0000x reference)
//
#include <hip/hip_runtime.h>
#include <hip/hip_bf16.h>
#include <stdint.h>

#define NN 100000
#define NE 3200000
#define EF 24
#define KF 536
#define BM 64
#define GSTRIDE 25
#define NGEMM 1563            // ceil(NN/64)
#define NSCAT 37500           // NE*6/512
#define NBLK (NGEMM + NSCAT)  // 39063
#define OUTB 204800000ULL     // out bytes

typedef __attribute__((ext_vector_type(8))) short bf16x8;
typedef __attribute__((ext_vector_type(8))) unsigned short u16x8;
typedef __attribute__((ext_vector_type(4))) float f32x4;

__device__ __forceinline__ unsigned short f2bf(float f) {
  union { float f; unsigned int u; } v; v.f = f;
  unsigned int r = v.u + 0x7FFFu + ((v.u >> 16) & 1u);
  return (unsigned short)(r >> 16);
}

__device__ __forceinline__ void gload_lds16(const void* g, void* l) {
  __builtin_amdgcn_global_load_lds(
      (const __attribute__((address_space(1))) unsigned int*)g,
      (__attribute__((address_space(3))) unsigned int*)l, 16, 0, 0);
}

// Wb_swz layout: [kt 0..16][nt 0..31][lane 0..63] x 16B, fragment-linear.
__global__ void wconv_kernel(const float* __restrict__ W, unsigned short* __restrict__ Wb) {
  int i = blockIdx.x * blockDim.x + threadIdx.x;  // over 17*32*64*8
  if (i >= 17 * 32 * 64 * 8) return;
  int j = i & 7;
  int lane = (i >> 3) & 63;
  int nt = (i >> 9) & 31;
  int kt = i >> 14;
  int row = nt * 16 + (lane & 15);
  int k = kt * 32 + (lane >> 4) * 8 + j;
  float v = (k < KF) ? W[row * KF + k] : 0.0f;
  Wb[i] = f2bf(v);
}

// Init: every 16-bit lane = 2^14 (bias absorbing negative partial sums).
__global__ __launch_bounds__(256) void init_u64_kernel(unsigned long long* __restrict__ acc) {
  int i = blockIdx.x * 256 + threadIdx.x;
  if (i < NN * 6) acc[i] = 0x4000400040004000ULL;
}

// Phase A: task-parallel fusion. Every GSTRIDE-th block = GEMM-main (k 0..511,
// PACKED f32 partial, thread-contiguous 256B, into out's own block range);
// others = scatter slices (u64 fixed-point atomics). Conflict-free A staging:
// thread t <-> LDS slot t (wave writes contiguous 1KB).
__global__ __launch_bounds__(512, 4) void fusedA_kernel(
    const float* __restrict__ h, const float* __restrict__ m,
    const int* __restrict__ dst, const unsigned short* __restrict__ Wb,
    unsigned long long* __restrict__ acc, float* __restrict__ out) {
  __shared__ __align__(16) unsigned short Alds[2 * 2048];   // 8KB
  __shared__ __align__(16) unsigned short Blds[2 * 16384];  // 64KB

  const int bid = blockIdx.x;
  const int t = threadIdx.x;

  if (bid % GSTRIDE != 0) {
    // ---------------- scatter role ----------------
    int sidx = bid - bid / GSTRIDE - 1;   // 0..NSCAT-1
    int i = sidx * 512 + t;               // < NE*6 exactly
    int e = i / 6;
    int fp = i - e * 6;
    float4 v = *(const float4*)(m + (size_t)e * EF + fp * 4);
    long long a0 = (long long)__float2int_rn(v.x * 128.f);
    long long a1 = (long long)__float2int_rn(v.y * 128.f);
    long long a2 = (long long)__float2int_rn(v.z * 128.f);
    long long a3 = (long long)__float2int_rn(v.w * 128.f);
    unsigned long long add = (unsigned long long)(a0 + (a1 << 16) + (a2 << 32) + (a3 << 48));
    atomicAdd(acc + (size_t)dst[e] * 6 + fp, add);
    return;
  }

  // ---------------- GEMM-main role (k 0..511) ----------------
  const int g = bid / GSTRIDE;  // 0..NGEMM-1
  const int lane = t & 63;
  const int w = t >> 6;
  const int mg = w >> 2;
  const int ng = w & 3;
  const int blockRow = g * BM;

  // Conflict-free A staging: thread t -> slot (t&255) in chunk (t>>8).
  const int kkA = t >> 8;
  const int sA = t & 255;
  const int rowA = ((sA >> 6) << 4) | (sA & 15);
  const int akgA = (sA >> 4) & 3;
  const int arow = blockRow + rowA;
  char* aldsdst = (char*)Alds + kkA * 4096 + sA * 16;
  const float* asrc = h + (size_t)arow * 512 + kkA * 32 + akgA * 8;

  f32x4 acc2[2][8];
#pragma unroll
  for (int i = 0; i < 2; ++i)
#pragma unroll
    for (int j = 0; j < 8; ++j) acc2[i][j] = (f32x4){0.f, 0.f, 0.f, 0.f};

  float4 ra0 = make_float4(0.f, 0.f, 0.f, 0.f), ra1 = ra0;
  if (arow < NN) {
    ra0 = *(const float4*)asrc;
    ra1 = *(const float4*)(asrc + 4);
  }

  for (int step = 0; step < 8; ++step) {
#pragma unroll
    for (int kk = 0; kk < 2; ++kk) {
      const unsigned short* src = Wb + ((size_t)((step * 2 + kk) * 32 + w) * 64 + lane) * 8;
#pragma unroll
      for (int j = 0; j < 4; ++j)
        gload_lds16(src + (size_t)j * 8 * 64 * 8, (char*)Blds + kk * 32768 + (j * 8 + w) * 1024);
    }
    {
      u16x8 bv;
      bv[0] = f2bf(ra0.x); bv[1] = f2bf(ra0.y); bv[2] = f2bf(ra0.z); bv[3] = f2bf(ra0.w);
      bv[4] = f2bf(ra1.x); bv[5] = f2bf(ra1.y); bv[6] = f2bf(ra1.z); bv[7] = f2bf(ra1.w);
      *(u16x8*)aldsdst = bv;  // contiguous 1KB per wave: conflict-free
    }
    ra0 = make_float4(0.f, 0.f, 0.f, 0.f); ra1 = ra0;
    if (step < 7 && arow < NN) {
      const float* p = asrc + (step + 1) * 64;
      ra0 = *(const float4*)p;
      ra1 = *(const float4*)(p + 4);
    }
    __syncthreads();

#pragma unroll
    for (int kk = 0; kk < 2; ++kk) {
      bf16x8 af0 = *(const bf16x8*)((const char*)Alds + kk * 4096 + (((mg * 2 + 0) * 64) + lane) * 16);
      bf16x8 af1 = *(const bf16x8*)((const char*)Alds + kk * 4096 + (((mg * 2 + 1) * 64) + lane) * 16);
#pragma unroll
      for (int j = 0; j < 8; ++j) {
        int nt = ng * 8 + j;
        bf16x8 bf = *(const bf16x8*)((const char*)Blds + kk * 32768 + ((nt * 64) + lane) * 16);
        acc2[0][j] = __builtin_amdgcn_mfma_f32_16x16x32_bf16(af0, bf, acc2[0][j], 0, 0, 0);
        acc2[1][j] = __builtin_amdgcn_mfma_f32_16x16x32_bf16(af1, bf, acc2[1][j], 0, 0, 0);
      }
    }
    __syncthreads();
  }

  // ---- PACKED partial store: 256B thread-contiguous into out's own range ----
  if ((size_t)g * 131072 + ((size_t)t + 1) * 256 <= OUTB) {
    float* pp = out + (size_t)g * 32768 + (size_t)t * 64;
#pragma unroll
    for (int mt = 0; mt < 2; ++mt)
#pragma unroll
      for (int j = 0; j < 8; ++j)
        *(f32x4*)(pp + (mt * 8 + j) * 4) = acc2[mt][j];
  }
}

// Phase B: decode acc -> A-frag (x norm), MFMA the 24-col tail, add packed
// partial, bias, LayerNorm, ReLU, store final (same byte range).
__global__ __launch_bounds__(512, 4) void epilogue_kernel(
    const unsigned long long* __restrict__ acc, const float* __restrict__ norm,
    const unsigned short* __restrict__ Wb,
    const float* __restrict__ bias, const float* __restrict__ gamma,
    const float* __restrict__ beta, float* __restrict__ out) {
  __shared__ __align__(16) unsigned short Alds[2048];   // 4KB
  __shared__ __align__(16) unsigned short Blds[16384];  // 32KB
  __shared__ float red[4][BM][2];
  __shared__ float stats[BM][2];

  const int t = threadIdx.x;
  const int lane = t & 63;
  const int w = t >> 6;
  const int lgrp = lane >> 4;
  const int llow = lane & 15;
  const int mg = w >> 2;
  const int ng = w & 3;
  const int g = blockIdx.x;
  const int blockRow = g * BM;

  // stage B: kt=16 slice (cols 512..543; 536+ zero-padded by wconv)
  {
    const unsigned short* src = Wb + ((size_t)(16 * 32 + w) * 64 + lane) * 8;
#pragma unroll
    for (int j = 0; j < 4; ++j)
      gload_lds16(src + (size_t)j * 8 * 64 * 8, (char*)Blds + (j * 8 + w) * 1024);
  }
  // decode acc -> A fragments (k = fp*4..fp*4+3), x norm, bf16
  if (t < 384) {
    int row = t / 6;
    int fp = t - row * 6;
    int nrow = blockRow + row;
    unsigned long long x = 0x4000400040004000ULL;
    float nv = 0.f;
    if (nrow < NN) {
      x = acc[(size_t)nrow * 6 + fp];
      nv = norm[nrow] * (1.0f / 128.0f);
    }
    ushort4 o;
    o.x = f2bf((float)((int)((x >> 0) & 0xFFFF) - 16384) * nv);
    o.y = f2bf((float)((int)((x >> 16) & 0xFFFF) - 16384) * nv);
    o.z = f2bf((float)((int)((x >> 32) & 0xFFFF) - 16384) * nv);
    o.w = f2bf((float)((int)((x >> 48) & 0xFFFF) - 16384) * nv);
    int akg = fp >> 1;
    int half = fp & 1;
    *(ushort4*)((char*)Alds + (((row >> 4) * 64 + akg * 16 + (row & 15)) * 16 + half * 8)) = o;
  } else {
    int tt = t - 384;        // 0..127
    int row = tt >> 1;       // 0..63
    int half = tt & 1;
    *(ushort4*)((char*)Alds + (((row >> 4) * 64 + 3 * 16 + (row & 15)) * 16 + half * 8)) =
        make_ushort4(0, 0, 0, 0);
  }
  __syncthreads();

  // MFMA tail: 16 per wave
  f32x4 acc2[2][8];
#pragma unroll
  for (int i = 0; i < 2; ++i)
#pragma unroll
    for (int j = 0; j < 8; ++j) acc2[i][j] = (f32x4){0.f, 0.f, 0.f, 0.f};
  {
    bf16x8 af0 = *(const bf16x8*)((const char*)Alds + (((mg * 2 + 0) * 64) + lane) * 16);
    bf16x8 af1 = *(const bf16x8*)((const char*)Alds + (((mg * 2 + 1) * 64) + lane) * 16);
#pragma unroll
    for (int j = 0; j < 8; ++j) {
      int nt = ng * 8 + j;
      bf16x8 bf = *(const bf16x8*)((const char*)Blds + ((nt * 64) + lane) * 16);
      acc2[0][j] = __builtin_amdgcn_mfma_f32_16x16x32_bf16(af0, bf, acc2[0][j], 0, 0, 0);
      acc2[1][j] = __builtin_amdgcn_mfma_f32_16x16x32_bf16(af1, bf, acc2[1][j], 0, 0, 0);
    }
  }

  // add PACKED partial (16 contiguous float4 per thread; same mapping as store)
  if ((size_t)g * 131072 + ((size_t)t + 1) * 256 <= OUTB) {
    const float* pp = out + (size_t)g * 32768 + (size_t)t * 64;
#pragma unroll
    for (int mt = 0; mt < 2; ++mt)
#pragma unroll
      for (int j = 0; j < 8; ++j) {
        f32x4 q = *(const f32x4*)(pp + (mt * 8 + j) * 4);
        acc2[mt][j][0] += q[0];
        acc2[mt][j][1] += q[1];
        acc2[mt][j][2] += q[2];
        acc2[mt][j][3] += q[3];
      }
  }

  // ---- bias, LN stats, normalize, relu, store ----
  float bcol[8], gcol[8], btcol[8];
#pragma unroll
  for (int j = 0; j < 8; ++j) {
    int col = (ng * 8 + j) * 16 + llow;
    bcol[j] = bias[col];
    gcol[j] = gamma[col];
    btcol[j] = beta[col];
  }
  float s[2][4], ss[2][4];
#pragma unroll
  for (int mt = 0; mt < 2; ++mt)
#pragma unroll
    for (int r = 0; r < 4; ++r) { s[mt][r] = 0.f; ss[mt][r] = 0.f; }
#pragma unroll
  for (int mt = 0; mt < 2; ++mt)
#pragma unroll
    for (int j = 0; j < 8; ++j)
#pragma unroll
      for (int r = 0; r < 4; ++r) {
        float v = acc2[mt][j][r] + bcol[j];
        acc2[mt][j][r] = v;
        s[mt][r] += v;
        ss[mt][r] += v * v;
      }
#pragma unroll
  for (int off = 1; off < 16; off <<= 1) {
#pragma unroll
    for (int mt = 0; mt < 2; ++mt)
#pragma unroll
      for (int r = 0; r < 4; ++r) {
        s[mt][r] += __shfl_xor(s[mt][r], off, 64);
        ss[mt][r] += __shfl_xor(ss[mt][r], off, 64);
      }
  }
  if (llow == 0) {
#pragma unroll
    for (int mt = 0; mt < 2; ++mt)
#pragma unroll
      for (int r = 0; r < 4; ++r) {
        int lrow = (mg * 2 + mt) * 16 + lgrp * 4 + r;
        red[ng][lrow][0] = s[mt][r];
        red[ng][lrow][1] = ss[mt][r];
      }
  }
  __syncthreads();
  if (t < BM) {
    float sum = red[0][t][0] + red[1][t][0] + red[2][t][0] + red[3][t][0];
    float sq = red[0][t][1] + red[1][t][1] + red[2][t][1] + red[3][t][1];
    float mean = sum * (1.0f / 512.0f);
    float var = sq * (1.0f / 512.0f) - mean * mean;
    stats[t][0] = mean;
    stats[t][1] = rsqrtf(var + 1e-5f);
  }
  __syncthreads();
#pragma unroll
  for (int mt = 0; mt < 2; ++mt) {
#pragma unroll
    for (int r = 0; r < 4; ++r) {
      int lrow = (mg * 2 + mt) * 16 + lgrp * 4 + r;
      int grow = blockRow + lrow;
      if (grow < NN) {
        float mean = stats[lrow][0];
        float rstd = stats[lrow][1];
#pragma unroll
        for (int j = 0; j < 8; ++j) {
          int col = (ng * 8 + j) * 16 + llow;
          float v = (acc2[mt][j][r] - mean) * rstd * gcol[j] + btcol[j];
          out[(size_t)grow * 512 + col] = fmaxf(v, 0.0f);
        }
      }
    }
  }
}

extern "C" void kernel_launch(void* const* d_in, const int* in_sizes, int n_in,
                              void* d_out, int out_size, void* d_ws, size_t ws_size,
                              hipStream_t stream) {
  const float* h = (const float*)d_in[0];
  const float* m = (const float*)d_in[1];
  const int* dst = (const int*)d_in[2];
  const float* norm = (const float*)d_in[3];
  const float* W = (const float*)d_in[4];
  const float* b = (const float*)d_in[5];
  const float* gamma = (const float*)d_in[6];
  const float* beta = (const float*)d_in[7];
  float* out = (float*)d_out;

  // ws usage 5.85 MB — strictly inside the PROVEN 10.16 MB footprint:
  //   Wb_swz @ 0         : 557,056 B
  //   acc    @ 1,048,576 : 4,800,000 B (u64 fixed-point accumulator)
  // GEMM partial lives PACKED in out's own per-block byte range (epilogue
  // block g reads exactly the bytes it rewrites -> no cross-block aliasing).
  unsigned short* Wb = (unsigned short*)d_ws;
  unsigned long long* acc = (unsigned long long*)((char*)d_ws + 1048576);

  init_u64_kernel<<<(NN * 6 + 255) / 256, 256, 0, stream>>>(acc);
  wconv_kernel<<<(17 * 32 * 64 * 8 + 255) / 256, 256, 0, stream>>>(W, Wb);
  fusedA_kernel<<<NBLK, 512, 0, stream>>>(h, m, dst, Wb, acc, out);
  epilogue_kernel<<<NGEMM, 512, 0, stream>>>(acc, norm, Wb, b, gamma, beta, out);
}

// Round 17
// 370.931 us; speedup vs baseline: 1.0768x; 1.0768x over previous
//
#include <hip/hip_runtime.h>
#include <hip/hip_bf16.h>
#include <stdint.h>

#define NN 100000
#define NE 3200000
#define EF 24
#define KF 536
#define BM 64

typedef __attribute__((ext_vector_type(8))) short bf16x8;
typedef __attribute__((ext_vector_type(8))) unsigned short u16x8;
typedef __attribute__((ext_vector_type(4))) float f32x4;

__device__ __forceinline__ unsigned short f2bf(float f) {
  union { float f; unsigned int u; } v; v.f = f;
  unsigned int r = v.u + 0x7FFFu + ((v.u >> 16) & 1u);
  return (unsigned short)(r >> 16);
}

__device__ __forceinline__ void gload_lds16(const void* g, void* l) {
  __builtin_amdgcn_global_load_lds(
      (const __attribute__((address_space(1))) unsigned int*)g,
      (__attribute__((address_space(3))) unsigned int*)l, 16, 0, 0);
}

// Wb_swz layout: [kt 0..16][nt 0..31][lane 0..63] x 16B, fragment-linear:
// lane l holds B[col = nt*16 + (l&15)][k = kt*32 + (l>>4)*8 .. +8).
__global__ void wconv_kernel(const float* __restrict__ W, unsigned short* __restrict__ Wb) {
  int i = blockIdx.x * blockDim.x + threadIdx.x;  // over 17*32*64*8
  if (i >= 17 * 32 * 64 * 8) return;
  int j = i & 7;
  int lane = (i >> 3) & 63;
  int nt = (i >> 9) & 31;
  int kt = i >> 14;
  int row = nt * 16 + (lane & 15);
  int k = kt * 32 + (lane >> 4) * 8 + j;
  float v = (k < KF) ? W[row * KF + k] : 0.0f;
  Wb[i] = f2bf(v);
}

// Init: every 16-bit lane = 2^14 (bias absorbing negative partial sums).
__global__ __launch_bounds__(256) void init_u64_kernel(unsigned long long* __restrict__ acc) {
  int i = blockIdx.x * 256 + threadIdx.x;
  if (i < NN * 6) acc[i] = 0x4000400040004000ULL;
}

// Segment-sum via u64 atomics, 4 x 16-bit fixed-point lanes (scale 128).
// Proven 220 us (coherence-point atomic-pipe data-BW floor).
__global__ __launch_bounds__(256) void scatter_u64_kernel(
    const float* __restrict__ m, const int* __restrict__ dst,
    unsigned long long* __restrict__ acc) {
  int i = blockIdx.x * 256 + threadIdx.x;
  if (i >= NE * 6) return;
  int e = i / 6;
  int fp = i - e * 6;
  float4 v = *(const float4*)(m + (size_t)e * EF + fp * 4);
  long long a0 = (long long)__float2int_rn(v.x * 128.f);
  long long a1 = (long long)__float2int_rn(v.y * 128.f);
  long long a2 = (long long)__float2int_rn(v.z * 128.f);
  long long a3 = (long long)__float2int_rn(v.w * 128.f);
  unsigned long long add = (unsigned long long)(a0 + (a1 << 16) + (a2 << 32) + (a3 << 48));
  atomicAdd(acc + (size_t)dst[e] * 6 + fp, add);
}

// ah[n][f] = (lane - 2^14) / 128 * norm[n]  (f32 out), fully coalesced.
__global__ __launch_bounds__(256) void decode_u64_kernel(
    const unsigned long long* __restrict__ acc, const float* __restrict__ norm,
    float* __restrict__ ah) {
  int i = blockIdx.x * 256 + threadIdx.x;  // over NN*6
  if (i >= NN * 6) return;
  int n = i / 6;
  unsigned long long x = acc[i];
  float nv = norm[n] * (1.0f / 128.0f);
  float4 o;
  o.x = (float)((int)((x >> 0) & 0xFFFF) - 16384) * nv;
  o.y = (float)((int)((x >> 16) & 0xFFFF) - 16384) * nv;
  o.z = (float)((int)((x >> 32) & 0xFFFF) - 16384) * nv;
  o.w = (float)((int)((x >> 48) & 0xFFFF) - 16384) * nv;
  *(float4*)(ah + (size_t)i * 4) = o;
}

// Fused GEMM (x = [h | ah_scaled], W^T) + bias + LayerNorm + ReLU.
// v6 = round-12 BK=64 structure + r15-proven CONFLICT-FREE A staging:
// thread t -> LDS slot (t&255) in chunk (t>>8); each wave's ds_write_b128 is
// a contiguous 1KB run (0 bank conflicts; was 8-way / 5.6M conflict cycles).
__global__ __launch_bounds__(512, 4) void gemm_ln_kernel(
    const float* __restrict__ h, const float* __restrict__ ah,
    const unsigned short* __restrict__ Wb,
    const float* __restrict__ bias, const float* __restrict__ gamma,
    const float* __restrict__ beta, float* __restrict__ out) {
  __shared__ __align__(16) unsigned short Alds[2 * 2048];   // 8KB  (kk-chunks of 4KB)
  __shared__ __align__(16) unsigned short Blds[2 * 16384];  // 64KB (kk-chunks of 32KB)
  __shared__ float red[4][BM][2];                           // 2KB
  __shared__ float stats[BM][2];

  const int t = threadIdx.x;
  const int lane = t & 63;
  const int w = t >> 6;
  const int lgrp = lane >> 4;
  const int llow = lane & 15;
  const int mg = w >> 2;  // 0..1
  const int ng = w & 3;   // 0..3
  const int blockRow = blockIdx.x * BM;

  // Conflict-free A staging: thread t -> slot sA=(t&255) in chunk kkA=(t>>8).
  // Slot sA holds row rowA, k-group akgA of the 32-k sub-slice.
  const int kkA = t >> 8;
  const int sA = t & 255;
  const int rowA = ((sA >> 6) << 4) | (sA & 15);
  const int akgA = (sA >> 4) & 3;
  const int arow = blockRow + rowA;
  char* aldsdst = (char*)Alds + kkA * 4096 + sA * 16;
  const float* asrc = h + (size_t)arow * 512 + kkA * 32 + akgA * 8;

  f32x4 acc[2][8];
#pragma unroll
  for (int i = 0; i < 2; ++i)
#pragma unroll
    for (int j = 0; j < 8; ++j) acc[i][j] = (f32x4){0.f, 0.f, 0.f, 0.f};

  // A prefetch registers (8 f32 = one 16B bf16 fragment after convert)
  float4 ra0 = make_float4(0.f, 0.f, 0.f, 0.f), ra1 = ra0;
  if (arow < NN) {
    ra0 = *(const float4*)asrc;
    ra1 = *(const float4*)(asrc + 4);
  }

  // ---- 8 full BK=64 steps over h (k 0..511) ----
  for (int step = 0; step < 8; ++step) {
    // stage B(step): 8 coalesced 1KB gload_lds (2 k-slices)
#pragma unroll
    for (int kk = 0; kk < 2; ++kk) {
      const unsigned short* src = Wb + ((size_t)((step * 2 + kk) * 32 + w) * 64 + lane) * 8;
#pragma unroll
      for (int j = 0; j < 4; ++j)
        gload_lds16(src + (size_t)j * 8 * 64 * 8, (char*)Blds + kk * 32768 + (j * 8 + w) * 1024);
    }
    // write A(step) from prefetch regs (contiguous 1KB per wave)
    {
      u16x8 bv;
      bv[0] = f2bf(ra0.x); bv[1] = f2bf(ra0.y); bv[2] = f2bf(ra0.z); bv[3] = f2bf(ra0.w);
      bv[4] = f2bf(ra1.x); bv[5] = f2bf(ra1.y); bv[6] = f2bf(ra1.z); bv[7] = f2bf(ra1.w);
      *(u16x8*)aldsdst = bv;
    }
    // prefetch A(step+1)
    ra0 = make_float4(0.f, 0.f, 0.f, 0.f); ra1 = ra0;
    if (arow < NN) {
      if (step < 7) {
        const float* p = asrc + (step + 1) * 64;
        ra0 = *(const float4*)p;
        ra1 = *(const float4*)(p + 4);
      } else if (kkA == 0 && akgA < 3) {  // tail: cols 512..535 = ah, rest zero
        const float* p = ah + (size_t)arow * EF + akgA * 8;
        ra0 = *(const float4*)p;
        ra1 = *(const float4*)(p + 4);
      }
    }
    __syncthreads();

    // MFMA: 2 kk x 8 n x 2 m = 32 per wave
#pragma unroll
    for (int kk = 0; kk < 2; ++kk) {
      bf16x8 af0 = *(const bf16x8*)((const char*)Alds + kk * 4096 + (((mg * 2 + 0) * 64) + lane) * 16);
      bf16x8 af1 = *(const bf16x8*)((const char*)Alds + kk * 4096 + (((mg * 2 + 1) * 64) + lane) * 16);
#pragma unroll
      for (int j = 0; j < 8; ++j) {
        int nt = ng * 8 + j;
        bf16x8 bf = *(const bf16x8*)((const char*)Blds + kk * 32768 + ((nt * 64) + lane) * 16);
        acc[0][j] = __builtin_amdgcn_mfma_f32_16x16x32_bf16(af0, bf, acc[0][j], 0, 0, 0);
        acc[1][j] = __builtin_amdgcn_mfma_f32_16x16x32_bf16(af1, bf, acc[1][j], 0, 0, 0);
      }
    }
    __syncthreads();
  }

  // ---- tail step: k 512..543 = [ah | zeros], BK=32 (chunk 0 only) ----
  {
    const unsigned short* src = Wb + ((size_t)(16 * 32 + w) * 64 + lane) * 8;
#pragma unroll
    for (int j = 0; j < 4; ++j)
      gload_lds16(src + (size_t)j * 8 * 64 * 8, (char*)Blds + (j * 8 + w) * 1024);
    if (kkA == 0) {  // chunk-0 threads carry the tail fragment (akgA==3 -> zeros)
      u16x8 bv;
      bv[0] = f2bf(ra0.x); bv[1] = f2bf(ra0.y); bv[2] = f2bf(ra0.z); bv[3] = f2bf(ra0.w);
      bv[4] = f2bf(ra1.x); bv[5] = f2bf(ra1.y); bv[6] = f2bf(ra1.z); bv[7] = f2bf(ra1.w);
      *(u16x8*)((char*)Alds + sA * 16) = bv;
    }
    __syncthreads();
    bf16x8 af0 = *(const bf16x8*)((const char*)Alds + (((mg * 2 + 0) * 64) + lane) * 16);
    bf16x8 af1 = *(const bf16x8*)((const char*)Alds + (((mg * 2 + 1) * 64) + lane) * 16);
#pragma unroll
    for (int j = 0; j < 8; ++j) {
      int nt = ng * 8 + j;
      bf16x8 bf = *(const bf16x8*)((const char*)Blds + ((nt * 64) + lane) * 16);
      acc[0][j] = __builtin_amdgcn_mfma_f32_16x16x32_bf16(af0, bf, acc[0][j], 0, 0, 0);
      acc[1][j] = __builtin_amdgcn_mfma_f32_16x16x32_bf16(af1, bf, acc[1][j], 0, 0, 0);
    }
  }

  // ---- epilogue: bias, LN stats, normalize, relu, store ----
  float bcol[8], gcol[8], btcol[8];
#pragma unroll
  for (int j = 0; j < 8; ++j) {
    int col = (ng * 8 + j) * 16 + llow;
    bcol[j] = bias[col];
    gcol[j] = gamma[col];
    btcol[j] = beta[col];
  }
  float s[2][4], ss[2][4];
#pragma unroll
  for (int mt = 0; mt < 2; ++mt)
#pragma unroll
    for (int r = 0; r < 4; ++r) { s[mt][r] = 0.f; ss[mt][r] = 0.f; }
#pragma unroll
  for (int mt = 0; mt < 2; ++mt)
#pragma unroll
    for (int j = 0; j < 8; ++j)
#pragma unroll
      for (int r = 0; r < 4; ++r) {
        float v = acc[mt][j][r] + bcol[j];
        acc[mt][j][r] = v;
        s[mt][r] += v;
        ss[mt][r] += v * v;
      }
#pragma unroll
  for (int off = 1; off < 16; off <<= 1) {
#pragma unroll
    for (int mt = 0; mt < 2; ++mt)
#pragma unroll
      for (int r = 0; r < 4; ++r) {
        s[mt][r] += __shfl_xor(s[mt][r], off, 64);
        ss[mt][r] += __shfl_xor(ss[mt][r], off, 64);
      }
  }
  if (llow == 0) {
#pragma unroll
    for (int mt = 0; mt < 2; ++mt)
#pragma unroll
      for (int r = 0; r < 4; ++r) {
        int lrow = (mg * 2 + mt) * 16 + lgrp * 4 + r;
        red[ng][lrow][0] = s[mt][r];
        red[ng][lrow][1] = ss[mt][r];
      }
  }
  __syncthreads();
  if (t < BM) {
    float sum = red[0][t][0] + red[1][t][0] + red[2][t][0] + red[3][t][0];
    float sq = red[0][t][1] + red[1][t][1] + red[2][t][1] + red[3][t][1];
    float mean = sum * (1.0f / 512.0f);
    float var = sq * (1.0f / 512.0f) - mean * mean;
    stats[t][0] = mean;
    stats[t][1] = rsqrtf(var + 1e-5f);
  }
  __syncthreads();
#pragma unroll
  for (int mt = 0; mt < 2; ++mt) {
#pragma unroll
    for (int r = 0; r < 4; ++r) {
      int lrow = (mg * 2 + mt) * 16 + lgrp * 4 + r;
      int grow = blockRow + lrow;
      if (grow < NN) {
        float mean = stats[lrow][0];
        float rstd = stats[lrow][1];
#pragma unroll
        for (int j = 0; j < 8; ++j) {
          int col = (ng * 8 + j) * 16 + llow;
          float v = (acc[mt][j][r] - mean) * rstd * gcol[j] + btcol[j];
          out[(size_t)grow * 512 + col] = fmaxf(v, 0.0f);
        }
      }
    }
  }
}

extern "C" void kernel_launch(void* const* d_in, const int* in_sizes, int n_in,
                              void* d_out, int out_size, void* d_ws, size_t ws_size,
                              hipStream_t stream) {
  const float* h = (const float*)d_in[0];
  const float* m = (const float*)d_in[1];
  const int* dst = (const int*)d_in[2];
  const float* norm = (const float*)d_in[3];
  const float* W = (const float*)d_in[4];
  const float* b = (const float*)d_in[5];
  const float* gamma = (const float*)d_in[6];
  const float* beta = (const float*)d_in[7];
  float* out = (float*)d_out;

  // ws: ah (9.6 MB) + Wb_swz (0.55 MB) — proven footprint.
  float* ah = (float*)d_ws;                                       // 9,600,000 B
  unsigned short* Wb = (unsigned short*)((char*)d_ws + 9600000);  // 557,056 B

  // u64 fixed-point accumulator lives in d_out (4.8 MB of 204.8 MB); GEMM
  // overwrites all of d_out afterwards.
  unsigned long long* acc = (unsigned long long*)d_out;  // NN*6 u64

  init_u64_kernel<<<(NN * 6 + 255) / 256, 256, 0, stream>>>(acc);
  wconv_kernel<<<(17 * 32 * 64 * 8 + 255) / 256, 256, 0, stream>>>(W, Wb);
  scatter_u64_kernel<<<(NE * 6 + 255) / 256, 256, 0, stream>>>(m, dst, acc);
  decode_u64_kernel<<<(NN * 6 + 255) / 256, 256, 0, stream>>>(acc, norm, ah);
  gemm_ln_kernel<<<(NN + BM - 1) / BM, 512, 0, stream>>>(h, ah, Wb, b, gamma, beta, out);
}

// Round 18
// 358.961 us; speedup vs baseline: 1.1127x; 1.0333x over previous
//
#include <hip/hip_runtime.h>
#include <hip/hip_bf16.h>
#include <stdint.h>

#define NN 100000
#define NE 3200000
#define EF 24
#define KF 536
#define BM 64

typedef __attribute__((ext_vector_type(8))) short bf16x8;
typedef __attribute__((ext_vector_type(8))) unsigned short u16x8;
typedef __attribute__((ext_vector_type(4))) float f32x4;

__device__ __forceinline__ unsigned short f2bf(float f) {
  union { float f; unsigned int u; } v; v.f = f;
  unsigned int r = v.u + 0x7FFFu + ((v.u >> 16) & 1u);
  return (unsigned short)(r >> 16);
}

__device__ __forceinline__ void gload_lds16(const void* g, void* l) {
  __builtin_amdgcn_global_load_lds(
      (const __attribute__((address_space(1))) unsigned int*)g,
      (__attribute__((address_space(3))) unsigned int*)l, 16, 0, 0);
}

// Wb_swz layout: [kt 0..16][nt 0..31][lane 0..63] x 16B, fragment-linear:
// lane l holds B[col = nt*16 + (l&15)][k = kt*32 + (l>>4)*8 .. +8).
__global__ void wconv_kernel(const float* __restrict__ W, unsigned short* __restrict__ Wb) {
  int i = blockIdx.x * blockDim.x + threadIdx.x;  // over 17*32*64*8
  if (i >= 17 * 32 * 64 * 8) return;
  int j = i & 7;
  int lane = (i >> 3) & 63;
  int nt = (i >> 9) & 31;
  int kt = i >> 14;
  int row = nt * 16 + (lane & 15);
  int k = kt * 32 + (lane >> 4) * 8 + j;
  float v = (k < KF) ? W[row * KF + k] : 0.0f;
  Wb[i] = f2bf(v);
}

// Init: every 16-bit lane = 2^14 (bias absorbing negative partial sums).
__global__ __launch_bounds__(256) void init_u64_kernel(unsigned long long* __restrict__ acc) {
  int i = blockIdx.x * 256 + threadIdx.x;
  if (i < NN * 6) acc[i] = 0x4000400040004000ULL;
}

// Segment-sum via u64 atomics, 4 x 16-bit fixed-point lanes (scale 128).
// Proven 220 us (coherence-point atomic-pipe data-BW floor).
__global__ __launch_bounds__(256) void scatter_u64_kernel(
    const float* __restrict__ m, const int* __restrict__ dst,
    unsigned long long* __restrict__ acc) {
  int i = blockIdx.x * 256 + threadIdx.x;
  if (i >= NE * 6) return;
  int e = i / 6;
  int fp = i - e * 6;
  float4 v = *(const float4*)(m + (size_t)e * EF + fp * 4);
  long long a0 = (long long)__float2int_rn(v.x * 128.f);
  long long a1 = (long long)__float2int_rn(v.y * 128.f);
  long long a2 = (long long)__float2int_rn(v.z * 128.f);
  long long a3 = (long long)__float2int_rn(v.w * 128.f);
  unsigned long long add = (unsigned long long)(a0 + (a1 << 16) + (a2 << 32) + (a3 << 48));
  atomicAdd(acc + (size_t)dst[e] * 6 + fp, add);
}

// Fused GEMM (x = [h | decode(acc)*norm], W^T) + bias + LayerNorm + ReLU.
// v7 = round-12 proven BK=64 structure (361.0 us pipeline), with the tail
// step's A-staging replaced by the r14/r15-proven acc->fragment decode
// (removes the decode_u64 kernel + the 9.6MB ah round-trip entirely).
__global__ __launch_bounds__(512, 4) void gemm_ln_kernel(
    const float* __restrict__ h, const unsigned long long* __restrict__ acc_in,
    const float* __restrict__ norm, const unsigned short* __restrict__ Wb,
    const float* __restrict__ bias, const float* __restrict__ gamma,
    const float* __restrict__ beta, float* __restrict__ out) {
  __shared__ __align__(16) unsigned short Alds[2 * 2048];   // 8KB  (kk-chunks of 4KB)
  __shared__ __align__(16) unsigned short Blds[2 * 16384];  // 64KB (kk-chunks of 32KB)
  __shared__ float red[4][BM][2];                           // 2KB
  __shared__ float stats[BM][2];

  const int t = threadIdx.x;
  const int lane = t & 63;
  const int w = t >> 6;
  const int lgrp = lane >> 4;
  const int llow = lane & 15;
  const int mg = w >> 2;  // 0..1
  const int ng = w & 3;   // 0..3
  const int blockRow = blockIdx.x * BM;

  // A staging (r12-proven): thread -> (row am, k-chunk c of 8); 16B per step.
  const int am = t >> 3;  // 0..63
  const int c = t & 7;    // 0..7 : k = c*8..c*8+7 within the 64-k step
  const int kkw = c >> 2; // which 4KB chunk
  const int akg = c & 3;
  const int arow = blockRow + am;
  char* aldsdst = (char*)Alds + kkw * 4096 + (((am >> 4) * 64 + akg * 16 + (am & 15)) * 16);

  f32x4 acc[2][8];
#pragma unroll
  for (int i = 0; i < 2; ++i)
#pragma unroll
    for (int j = 0; j < 8; ++j) acc[i][j] = (f32x4){0.f, 0.f, 0.f, 0.f};

  // A prefetch registers (8 f32 = one 16B fragment)
  float4 ra0 = make_float4(0.f, 0.f, 0.f, 0.f), ra1 = ra0;
  if (arow < NN) {
    const float* p = h + (size_t)arow * 512 + c * 8;
    ra0 = *(const float4*)p;
    ra1 = *(const float4*)(p + 4);
  }

  // ---- 8 full BK=64 steps over h (k 0..511) ----
  for (int step = 0; step < 8; ++step) {
    // stage B(step): 8 coalesced 1KB gload_lds (2 k-slices)
#pragma unroll
    for (int kk = 0; kk < 2; ++kk) {
      const unsigned short* src = Wb + ((size_t)((step * 2 + kk) * 32 + w) * 64 + lane) * 8;
#pragma unroll
      for (int j = 0; j < 4; ++j)
        gload_lds16(src + (size_t)j * 8 * 64 * 8, (char*)Blds + kk * 32768 + (j * 8 + w) * 1024);
    }
    // write A(step) from prefetch regs
    {
      u16x8 bv;
      bv[0] = f2bf(ra0.x); bv[1] = f2bf(ra0.y); bv[2] = f2bf(ra0.z); bv[3] = f2bf(ra0.w);
      bv[4] = f2bf(ra1.x); bv[5] = f2bf(ra1.y); bv[6] = f2bf(ra1.z); bv[7] = f2bf(ra1.w);
      *(u16x8*)aldsdst = bv;
    }
    // prefetch A(step+1)
    ra0 = make_float4(0.f, 0.f, 0.f, 0.f); ra1 = ra0;
    if (step < 7 && arow < NN) {
      const float* p = h + (size_t)arow * 512 + (step + 1) * 64 + c * 8;
      ra0 = *(const float4*)p;
      ra1 = *(const float4*)(p + 4);
    }
    __syncthreads();

    // MFMA: 2 kk x 8 n x 2 m = 32 per wave
#pragma unroll
    for (int kk = 0; kk < 2; ++kk) {
      bf16x8 af0 = *(const bf16x8*)((const char*)Alds + kk * 4096 + (((mg * 2 + 0) * 64) + lane) * 16);
      bf16x8 af1 = *(const bf16x8*)((const char*)Alds + kk * 4096 + (((mg * 2 + 1) * 64) + lane) * 16);
#pragma unroll
      for (int j = 0; j < 8; ++j) {
        int nt = ng * 8 + j;
        bf16x8 bf = *(const bf16x8*)((const char*)Blds + kk * 32768 + ((nt * 64) + lane) * 16);
        acc[0][j] = __builtin_amdgcn_mfma_f32_16x16x32_bf16(af0, bf, acc[0][j], 0, 0, 0);
        acc[1][j] = __builtin_amdgcn_mfma_f32_16x16x32_bf16(af1, bf, acc[1][j], 0, 0, 0);
      }
    }
    __syncthreads();
  }

  // ---- tail step: k 512..543 = [decode(acc)*norm | zeros] (r14/r15-proven) ----
  {
    const unsigned short* src = Wb + ((size_t)(16 * 32 + w) * 64 + lane) * 8;
#pragma unroll
    for (int j = 0; j < 4; ++j)
      gload_lds16(src + (size_t)j * 8 * 64 * 8, (char*)Blds + (j * 8 + w) * 1024);
    // decode acc -> A fragments (k = fp*4..fp*4+3), x norm, bf16
    if (t < 384) {
      int row = t / 6;
      int fp = t - row * 6;
      int nrow = blockRow + row;
      unsigned long long x = 0x4000400040004000ULL;
      float nv = 0.f;
      if (nrow < NN) {
        x = acc_in[(size_t)nrow * 6 + fp];
        nv = norm[nrow] * (1.0f / 128.0f);
      }
      ushort4 o;
      o.x = f2bf((float)((int)((x >> 0) & 0xFFFF) - 16384) * nv);
      o.y = f2bf((float)((int)((x >> 16) & 0xFFFF) - 16384) * nv);
      o.z = f2bf((float)((int)((x >> 32) & 0xFFFF) - 16384) * nv);
      o.w = f2bf((float)((int)((x >> 48) & 0xFFFF) - 16384) * nv);
      int akgd = fp >> 1;
      int half = fp & 1;
      *(ushort4*)((char*)Alds + (((row >> 4) * 64 + akgd * 16 + (row & 15)) * 16 + half * 8)) = o;
    } else {
      int tt = t - 384;        // 0..127: zero the akg==3 region (k 24..31 pad)
      int row = tt >> 1;       // 0..63
      int half = tt & 1;
      *(ushort4*)((char*)Alds + (((row >> 4) * 64 + 3 * 16 + (row & 15)) * 16 + half * 8)) =
          make_ushort4(0, 0, 0, 0);
    }
    __syncthreads();
    bf16x8 af0 = *(const bf16x8*)((const char*)Alds + (((mg * 2 + 0) * 64) + lane) * 16);
    bf16x8 af1 = *(const bf16x8*)((const char*)Alds + (((mg * 2 + 1) * 64) + lane) * 16);
#pragma unroll
    for (int j = 0; j < 8; ++j) {
      int nt = ng * 8 + j;
      bf16x8 bf = *(const bf16x8*)((const char*)Blds + ((nt * 64) + lane) * 16);
      acc[0][j] = __builtin_amdgcn_mfma_f32_16x16x32_bf16(af0, bf, acc[0][j], 0, 0, 0);
      acc[1][j] = __builtin_amdgcn_mfma_f32_16x16x32_bf16(af1, bf, acc[1][j], 0, 0, 0);
    }
  }

  // ---- epilogue: bias, LN stats, normalize, relu, store ----
  float bcol[8], gcol[8], btcol[8];
#pragma unroll
  for (int j = 0; j < 8; ++j) {
    int col = (ng * 8 + j) * 16 + llow;
    bcol[j] = bias[col];
    gcol[j] = gamma[col];
    btcol[j] = beta[col];
  }
  float s[2][4], ss[2][4];
#pragma unroll
  for (int mt = 0; mt < 2; ++mt)
#pragma unroll
    for (int r = 0; r < 4; ++r) { s[mt][r] = 0.f; ss[mt][r] = 0.f; }
#pragma unroll
  for (int mt = 0; mt < 2; ++mt)
#pragma unroll
    for (int j = 0; j < 8; ++j)
#pragma unroll
      for (int r = 0; r < 4; ++r) {
        float v = acc[mt][j][r] + bcol[j];
        acc[mt][j][r] = v;
        s[mt][r] += v;
        ss[mt][r] += v * v;
      }
#pragma unroll
  for (int off = 1; off < 16; off <<= 1) {
#pragma unroll
    for (int mt = 0; mt < 2; ++mt)
#pragma unroll
      for (int r = 0; r < 4; ++r) {
        s[mt][r] += __shfl_xor(s[mt][r], off, 64);
        ss[mt][r] += __shfl_xor(ss[mt][r], off, 64);
      }
  }
  if (llow == 0) {
#pragma unroll
    for (int mt = 0; mt < 2; ++mt)
#pragma unroll
      for (int r = 0; r < 4; ++r) {
        int lrow = (mg * 2 + mt) * 16 + lgrp * 4 + r;
        red[ng][lrow][0] = s[mt][r];
        red[ng][lrow][1] = ss[mt][r];
      }
  }
  __syncthreads();
  if (t < BM) {
    float sum = red[0][t][0] + red[1][t][0] + red[2][t][0] + red[3][t][0];
    float sq = red[0][t][1] + red[1][t][1] + red[2][t][1] + red[3][t][1];
    float mean = sum * (1.0f / 512.0f);
    float var = sq * (1.0f / 512.0f) - mean * mean;
    stats[t][0] = mean;
    stats[t][1] = rsqrtf(var + 1e-5f);
  }
  __syncthreads();
#pragma unroll
  for (int mt = 0; mt < 2; ++mt) {
#pragma unroll
    for (int r = 0; r < 4; ++r) {
      int lrow = (mg * 2 + mt) * 16 + lgrp * 4 + r;
      int grow = blockRow + lrow;
      if (grow < NN) {
        float mean = stats[lrow][0];
        float rstd = stats[lrow][1];
#pragma unroll
        for (int j = 0; j < 8; ++j) {
          int col = (ng * 8 + j) * 16 + llow;
          float v = (acc[mt][j][r] - mean) * rstd * gcol[j] + btcol[j];
          out[(size_t)grow * 512 + col] = fmaxf(v, 0.0f);
        }
      }
    }
  }
}

extern "C" void kernel_launch(void* const* d_in, const int* in_sizes, int n_in,
                              void* d_out, int out_size, void* d_ws, size_t ws_size,
                              hipStream_t stream) {
  const float* h = (const float*)d_in[0];
  const float* m = (const float*)d_in[1];
  const int* dst = (const int*)d_in[2];
  const float* norm = (const float*)d_in[3];
  const float* W = (const float*)d_in[4];
  const float* b = (const float*)d_in[5];
  const float* gamma = (const float*)d_in[6];
  const float* beta = (const float*)d_in[7];
  float* out = (float*)d_out;

  // ws usage 5.85 MB — the exact r14/r15-proven layout, inside the proven
  // 10.16 MB footprint:
  //   Wb_swz @ 0         : 557,056 B
  //   acc    @ 1,048,576 : 4,800,000 B (u64 fixed-point accumulator)
  // No d_out scratch use: gemm reads acc from ws while writing out.
  unsigned short* Wb = (unsigned short*)d_ws;
  unsigned long long* acc = (unsigned long long*)((char*)d_ws + 1048576);

  init_u64_kernel<<<(NN * 6 + 255) / 256, 256, 0, stream>>>(acc);
  wconv_kernel<<<(17 * 32 * 64 * 8 + 255) / 256, 256, 0, stream>>>(W, Wb);
  scatter_u64_kernel<<<(NE * 6 + 255) / 256, 256, 0, stream>>>(m, dst, acc);
  gemm_ln_kernel<<<(NN + BM - 1) / BM, 512, 0, stream>>>(h, acc, norm, Wb, b, gamma, beta, out);
}